// Round 1
// baseline (274.893 us; speedup 1.0000x reference)
//
#include <hip/hip_runtime.h>

// Multi-scale deformable attention, fp32.
// shapes: bs=8, nq=900, nh=8, d=32, nl=4, npt=4
// value: (bs, NUM_KEYS, nh, d), NUM_KEYS = 22223
// sampling_locations: (bs, nq, nh, nl, npt, 2)
// attention_weights:  (bs, nq, nh, nl, npt)
// out: (bs, nq, nh*d)

#define BS 8
#define NQ 900
#define NH 8
#define DD 32
#define NL 4
#define NPT 4
#define NUM_KEYS 22223

__global__ __launch_bounds__(256) void msda_kernel(
    const float* __restrict__ value,
    const float* __restrict__ loc,
    const float* __restrict__ aw,
    float* __restrict__ out)
{
    // thread layout: 8 lanes (float4 each) cover d=32 for one (b,q,h)
    const int tid = blockIdx.x * blockDim.x + threadIdx.x;
    const int cg = tid & 7;            // channel group: floats [cg*4, cg*4+4)
    const int h  = (tid >> 3) & 7;
    const int bq = tid >> 6;           // b*NQ + q
    const int b  = bq / NQ;

    // per-level H, W, start offset
    const int Hs[NL]  = {100, 50, 25, 13};
    const int Ws[NL]  = {167, 84, 42, 21};
    const int Sts[NL] = {0, 16700, 20900, 21950};

    const float4* __restrict__ v4 = (const float4*)value;
    // value float4 index: ((b*NUM_KEYS + key)*NH + h)*8 + cg
    const long vbase = ((long)b * NUM_KEYS) * (NH * 8) + h * 8 + cg;

    const float2* __restrict__ loc2 = (const float2*)loc;
    // loc2 / aw index: ((bq*NH + h)*NL + lvl)*NPT + p
    const int lbase = (bq * NH + h) * (NL * NPT);

    float4 acc = {0.f, 0.f, 0.f, 0.f};

    #pragma unroll
    for (int lvl = 0; lvl < NL; ++lvl) {
        const int H = Hs[lvl], W = Ws[lvl];
        const long lvbase = vbase + (long)Sts[lvl] * (NH * 8);
        const long rowstride = (long)W * (NH * 8);

        #pragma unroll
        for (int p = 0; p < NPT; ++p) {
            const int li = lbase + lvl * NPT + p;
            const float2 xy = loc2[li];
            const float w  = aw[li];

            const float x = xy.x * (float)W - 0.5f;
            const float y = xy.y * (float)H - 0.5f;
            const float fx0 = floorf(x);
            const float fy0 = floorf(y);
            const int x0 = (int)fx0;
            const int y0 = (int)fy0;
            const float wx1 = x - fx0, wy1 = y - fy0;
            const float wx0 = 1.f - wx1, wy0 = 1.f - wy1;

            const bool vx0 = (x0 >= 0) & (x0 < W);
            const bool vx1 = (x0 + 1 >= 0) & (x0 + 1 < W);
            const bool vy0 = (y0 >= 0) & (y0 < H);
            const bool vy1 = (y0 + 1 >= 0) & (y0 + 1 < H);

            const long rowy0 = lvbase + (long)y0 * rowstride;
            const long rowy1 = rowy0 + rowstride;

            if (vy0) {
                if (vx0) {
                    const float4 v = v4[rowy0 + (long)x0 * (NH * 8)];
                    const float s = w * (wx0 * wy0);
                    acc.x += s * v.x; acc.y += s * v.y;
                    acc.z += s * v.z; acc.w += s * v.w;
                }
                if (vx1) {
                    const float4 v = v4[rowy0 + (long)(x0 + 1) * (NH * 8)];
                    const float s = w * (wx1 * wy0);
                    acc.x += s * v.x; acc.y += s * v.y;
                    acc.z += s * v.z; acc.w += s * v.w;
                }
            }
            if (vy1) {
                if (vx0) {
                    const float4 v = v4[rowy1 + (long)x0 * (NH * 8)];
                    const float s = w * (wx0 * wy1);
                    acc.x += s * v.x; acc.y += s * v.y;
                    acc.z += s * v.z; acc.w += s * v.w;
                }
                if (vx1) {
                    const float4 v = v4[rowy1 + (long)(x0 + 1) * (NH * 8)];
                    const float s = w * (wx1 * wy1);
                    acc.x += s * v.x; acc.y += s * v.y;
                    acc.z += s * v.z; acc.w += s * v.w;
                }
            }
        }
    }

    float4* __restrict__ out4 = (float4*)out;
    out4[(bq * NH + h) * 8 + cg] = acc;
}

extern "C" void kernel_launch(void* const* d_in, const int* in_sizes, int n_in,
                              void* d_out, int out_size, void* d_ws, size_t ws_size,
                              hipStream_t stream) {
    const float* value = (const float*)d_in[0];
    const float* loc   = (const float*)d_in[1];
    const float* aw    = (const float*)d_in[2];
    float* out = (float*)d_out;

    // total threads: BS*NQ*NH*8 = 460800 -> 1800 blocks of 256 (exact)
    const int total = BS * NQ * NH * 8;
    const int block = 256;
    const int grid = total / block;
    msda_kernel<<<grid, block, 0, stream>>>(value, loc, aw, out);
}

// Round 2
// 260.155 us; speedup vs baseline: 1.0567x; 1.0567x over previous
//
#include <hip/hip_runtime.h>

// Multi-scale deformable attention, fp32 — branchless gather version.
// shapes: bs=8, nq=900, nh=8, d=32, nl=4, npt=4
// value: (bs, NUM_KEYS, nh, d), NUM_KEYS = 22223
// sampling_locations: (bs, nq, nh, nl, npt, 2)
// attention_weights:  (bs, nq, nh, nl, npt)
// out: (bs, nq, nh*d)

#define BS 8
#define NQ 900
#define NH 8
#define DD 32
#define NL 4
#define NPT 4
#define NUM_KEYS 22223

__global__ __launch_bounds__(256) void msda_kernel(
    const float* __restrict__ value,
    const float* __restrict__ loc,
    const float* __restrict__ aw,
    float* __restrict__ out)
{
    // thread layout: 8 lanes (float4 each) cover d=32 for one (b,q,h)
    const int tid = blockIdx.x * blockDim.x + threadIdx.x;
    const int cg = tid & 7;            // channel group: floats [cg*4, cg*4+4)
    const int h  = (tid >> 3) & 7;
    const int bq = tid >> 6;           // b*NQ + q
    const int b  = bq / NQ;

    const int Hs[NL]  = {100, 50, 25, 13};
    const int Ws[NL]  = {167, 84, 42, 21};
    const int Sts[NL] = {0, 16700, 20900, 21950};

    const float4* __restrict__ v4 = (const float4*)value;
    // value float4 index: ((b*NUM_KEYS + key)*NH + h)*8 + cg  — fits in 32 bits (max ~11.4M)
    const unsigned vbase = (unsigned)b * (NUM_KEYS * NH * 8) + h * 8 + cg;

    const float2* __restrict__ loc2 = (const float2*)loc;
    const int lbase = (bq * NH + h) * (NL * NPT);

    float4 acc = {0.f, 0.f, 0.f, 0.f};

    #pragma unroll
    for (int lvl = 0; lvl < NL; ++lvl) {
        const int H = Hs[lvl], W = Ws[lvl];
        const unsigned lvbase = vbase + (unsigned)Sts[lvl] * (NH * 8);
        const unsigned rowstride = (unsigned)W * (NH * 8);

        #pragma unroll
        for (int p = 0; p < NPT; ++p) {
            const int li = lbase + lvl * NPT + p;
            const float2 xy = loc2[li];
            const float w  = aw[li];

            const float x = xy.x * (float)W - 0.5f;
            const float y = xy.y * (float)H - 0.5f;
            const float fx0 = floorf(x);
            const float fy0 = floorf(y);
            const int x0 = (int)fx0;
            const int y0 = (int)fy0;
            float wx1 = x - fx0, wy1 = y - fy0;
            float wx0 = 1.f - wx1, wy0 = 1.f - wy1;

            // zero out-of-bounds corner weights instead of branching
            wx0 = (x0 >= 0 && x0 <= W - 1)     ? wx0 : 0.f;
            wx1 = (x0 + 1 >= 0 && x0 + 1 <= W - 1) ? wx1 : 0.f;
            wy0 = (y0 >= 0 && y0 <= H - 1)     ? wy0 : 0.f;
            wy1 = (y0 + 1 >= 0 && y0 + 1 <= H - 1) ? wy1 : 0.f;

            // clamped (always-legal) indices
            const int x0c = min(max(x0, 0), W - 1);
            const int x1c = min(max(x0 + 1, 0), W - 1);
            const int y0c = min(max(y0, 0), H - 1);
            const int y1c = min(max(y0 + 1, 0), H - 1);

            const unsigned r0 = lvbase + (unsigned)y0c * rowstride;
            const unsigned r1 = lvbase + (unsigned)y1c * rowstride;

            // 4 unconditional, independent gathers
            const float4 v00 = v4[r0 + (unsigned)x0c * (NH * 8)];
            const float4 v01 = v4[r0 + (unsigned)x1c * (NH * 8)];
            const float4 v10 = v4[r1 + (unsigned)x0c * (NH * 8)];
            const float4 v11 = v4[r1 + (unsigned)x1c * (NH * 8)];

            const float s00 = w * wx0 * wy0;
            const float s01 = w * wx1 * wy0;
            const float s10 = w * wx0 * wy1;
            const float s11 = w * wx1 * wy1;

            acc.x = fmaf(s00, v00.x, acc.x); acc.y = fmaf(s00, v00.y, acc.y);
            acc.z = fmaf(s00, v00.z, acc.z); acc.w = fmaf(s00, v00.w, acc.w);
            acc.x = fmaf(s01, v01.x, acc.x); acc.y = fmaf(s01, v01.y, acc.y);
            acc.z = fmaf(s01, v01.z, acc.z); acc.w = fmaf(s01, v01.w, acc.w);
            acc.x = fmaf(s10, v10.x, acc.x); acc.y = fmaf(s10, v10.y, acc.y);
            acc.z = fmaf(s10, v10.z, acc.z); acc.w = fmaf(s10, v10.w, acc.w);
            acc.x = fmaf(s11, v11.x, acc.x); acc.y = fmaf(s11, v11.y, acc.y);
            acc.z = fmaf(s11, v11.z, acc.z); acc.w = fmaf(s11, v11.w, acc.w);
        }
    }

    float4* __restrict__ out4 = (float4*)out;
    out4[(bq * NH + h) * 8 + cg] = acc;
}

extern "C" void kernel_launch(void* const* d_in, const int* in_sizes, int n_in,
                              void* d_out, int out_size, void* d_ws, size_t ws_size,
                              hipStream_t stream) {
    const float* value = (const float*)d_in[0];
    const float* loc   = (const float*)d_in[1];
    const float* aw    = (const float*)d_in[2];
    float* out = (float*)d_out;

    const int total = BS * NQ * NH * 8;   // 460800 threads
    const int block = 256;
    const int grid = total / block;       // 1800 blocks, exact
    msda_kernel<<<grid, block, 0, stream>>>(value, loc, aw, out);
}

// Round 3
// 253.990 us; speedup vs baseline: 1.0823x; 1.0243x over previous
//
#include <hip/hip_runtime.h>

// Multi-scale deformable attention, fp32 — level-parallel version.
// thread = (bq, h, lvl, cg): 4 level-threads reduce via __shfl_xor (lanes 3-4).
// shapes: bs=8, nq=900, nh=8, d=32, nl=4, npt=4
// value: (bs, NUM_KEYS, nh, d), NUM_KEYS = 22223

#define BS 8
#define NQ 900
#define NH 8
#define NL 4
#define NPT 4
#define NUM_KEYS 22223

__global__ __launch_bounds__(256) void msda_kernel(
    const float* __restrict__ value,
    const float* __restrict__ loc,
    const float* __restrict__ aw,
    float* __restrict__ out)
{
    const int tid = blockIdx.x * 256 + threadIdx.x;
    const int cg  = tid & 7;           // channel group: floats [cg*4, cg*4+4)
    const int lvl = (tid >> 3) & 3;    // level (lane bits 3-4 -> intra-wave reduce)
    const int h   = (tid >> 5) & 7;
    const int bq  = tid >> 8;          // b*NQ + q
    const int b   = bq / NQ;

    // per-thread level constants via cndmask chains (no scratch arrays)
    const bool l01 = lvl < 2;
    const int H  = l01 ? (lvl == 0 ? 100 : 50)    : (lvl == 2 ? 25 : 13);
    const int W  = l01 ? (lvl == 0 ? 167 : 84)    : (lvl == 2 ? 42 : 21);
    const int St = l01 ? (lvl == 0 ? 0 : 16700)   : (lvl == 2 ? 20900 : 21950);

    const float4* __restrict__ v4 = (const float4*)value;
    // value float4 index: ((b*NUM_KEYS + key)*NH + h)*8 + cg  — fits in 32 bits
    const unsigned vbase = (unsigned)b * (NUM_KEYS * NH * 8) + h * 8 + cg
                         + (unsigned)St * (NH * 8);
    const unsigned rowstride = (unsigned)W * (NH * 8);

    // loc: (..., lvl, npt, 2) -> 4 points = 2 float4; aw -> 1 float4
    const int lidx = (bq * NH + h) * NL + lvl;
    const float4* __restrict__ loc4 = (const float4*)loc;
    const float4* __restrict__ aw4  = (const float4*)aw;
    const float4 xy01 = loc4[lidx * 2];
    const float4 xy23 = loc4[lidx * 2 + 1];
    const float4 wv   = aw4[lidx];

    const float xs[NPT] = {xy01.x, xy01.z, xy23.x, xy23.z};
    const float ys[NPT] = {xy01.y, xy01.w, xy23.y, xy23.w};
    const float ws[NPT] = {wv.x, wv.y, wv.z, wv.w};

    float4 acc = {0.f, 0.f, 0.f, 0.f};

    #pragma unroll
    for (int p = 0; p < NPT; ++p) {
        const float x = xs[p] * (float)W - 0.5f;
        const float y = ys[p] * (float)H - 0.5f;
        const float w = ws[p];
        const float fx0 = floorf(x);
        const float fy0 = floorf(y);
        const int x0 = (int)fx0;
        const int y0 = (int)fy0;
        float wx1 = x - fx0, wy1 = y - fy0;
        float wx0 = 1.f - wx1, wy0 = 1.f - wy1;

        // zero out-of-bounds corner weights instead of branching
        wx0 = (x0 >= 0 && x0 <= W - 1)         ? wx0 : 0.f;
        wx1 = (x0 + 1 >= 0 && x0 + 1 <= W - 1) ? wx1 : 0.f;
        wy0 = (y0 >= 0 && y0 <= H - 1)         ? wy0 : 0.f;
        wy1 = (y0 + 1 >= 0 && y0 + 1 <= H - 1) ? wy1 : 0.f;

        const int x0c = min(max(x0, 0), W - 1);
        const int x1c = min(max(x0 + 1, 0), W - 1);
        const int y0c = min(max(y0, 0), H - 1);
        const int y1c = min(max(y0 + 1, 0), H - 1);

        const unsigned r0 = vbase + (unsigned)y0c * rowstride;
        const unsigned r1 = vbase + (unsigned)y1c * rowstride;

        const float4 v00 = v4[r0 + (unsigned)x0c * (NH * 8)];
        const float4 v01 = v4[r0 + (unsigned)x1c * (NH * 8)];
        const float4 v10 = v4[r1 + (unsigned)x0c * (NH * 8)];
        const float4 v11 = v4[r1 + (unsigned)x1c * (NH * 8)];

        const float s00 = w * wx0 * wy0;
        const float s01 = w * wx1 * wy0;
        const float s10 = w * wx0 * wy1;
        const float s11 = w * wx1 * wy1;

        acc.x = fmaf(s00, v00.x, acc.x); acc.y = fmaf(s00, v00.y, acc.y);
        acc.z = fmaf(s00, v00.z, acc.z); acc.w = fmaf(s00, v00.w, acc.w);
        acc.x = fmaf(s01, v01.x, acc.x); acc.y = fmaf(s01, v01.y, acc.y);
        acc.z = fmaf(s01, v01.z, acc.z); acc.w = fmaf(s01, v01.w, acc.w);
        acc.x = fmaf(s10, v10.x, acc.x); acc.y = fmaf(s10, v10.y, acc.y);
        acc.z = fmaf(s10, v10.z, acc.z); acc.w = fmaf(s10, v10.w, acc.w);
        acc.x = fmaf(s11, v11.x, acc.x); acc.y = fmaf(s11, v11.y, acc.y);
        acc.z = fmaf(s11, v11.z, acc.z); acc.w = fmaf(s11, v11.w, acc.w);
    }

    // reduce across the 4 level-threads (lane bits 3 and 4)
    acc.x += __shfl_xor(acc.x, 8);  acc.y += __shfl_xor(acc.y, 8);
    acc.z += __shfl_xor(acc.z, 8);  acc.w += __shfl_xor(acc.w, 8);
    acc.x += __shfl_xor(acc.x, 16); acc.y += __shfl_xor(acc.y, 16);
    acc.z += __shfl_xor(acc.z, 16); acc.w += __shfl_xor(acc.w, 16);

    if (lvl == 0) {
        float4* __restrict__ out4 = (float4*)out;
        out4[(bq * NH + h) * 8 + cg] = acc;
    }
}

extern "C" void kernel_launch(void* const* d_in, const int* in_sizes, int n_in,
                              void* d_out, int out_size, void* d_ws, size_t ws_size,
                              hipStream_t stream) {
    const float* value = (const float*)d_in[0];
    const float* loc   = (const float*)d_in[1];
    const float* aw    = (const float*)d_in[2];
    float* outp = (float*)d_out;

    const int total = BS * NQ * NH * NL * 8;  // 1,843,200 threads
    const int block = 256;
    const int grid = total / block;           // 7200 blocks, exact
    msda_kernel<<<grid, block, 0, stream>>>(value, loc, aw, outp);
}